// Round 10
// baseline (990.446 us; speedup 1.0000x reference)
//
#include <hip/hip_runtime.h>

#define N_ENTITIES 200000
#define N_ITEMS    100000
#define DIM        64
#define N_EDGES    1500000
#define K_EDGES    256
#define K_ITEMS    100
// 1 / (2 * sqrt(32))  (mean over 2 heads of per-head 1/sqrt(Dk))
#define SCALE      0.08838834764831845f

#define CAND_CAP   4096
#define NSCANB     ((N_ENTITIES + 255) / 256)   // 782
#define CAP        128                          // per-node exp-logit stash (max degree ~35)

typedef unsigned long long u64;

// ---- monotonic float<->u32 key (order-preserving, total order) ----
__device__ __forceinline__ unsigned fkey(float x) {
    unsigned u = __float_as_uint(x);
    return (u & 0x80000000u) ? ~u : (u | 0x80000000u);
}
__device__ __forceinline__ float funkey(unsigned k) {
    return (k & 0x80000000u) ? __uint_as_float(k & 0x7fffffffu)
                             : __uint_as_float(~k);
}

__device__ __forceinline__ unsigned xcc_id() {
    unsigned x;
    asm volatile("s_getreg_b32 %0, hwreg(HW_REG_XCC_ID)" : "=s"(x));
    return x;
}

// wave-aggregated LDS histogram add: one LDS atomic per distinct bin per wave
__device__ __forceinline__ void lds_hist_add(unsigned* h, unsigned bin, bool valid, int lane) {
    bool need = valid;
    for (;;) {
        unsigned long long mask = __ballot(need);
        if (mask == 0ull) break;
        int leader = __ffsll(mask) - 1;
        unsigned lbin = __shfl(bin, leader, 64);
        bool same = need && (bin == lbin);
        unsigned long long grp = __ballot(same);
        if (lane == leader) atomicAdd(&h[lbin], (unsigned)__popcll(grp));
        need = need && !same;
    }
}

// serial 256-bin select: largest bin b with count(>b) < Keff <= count(>=b).
__device__ __forceinline__ unsigned select_digit(const unsigned* __restrict__ hist,
                                                 unsigned Keff, unsigned* above) {
    unsigned cum = 0;
    int b = 255;
    for (; b > 0; --b) {
        unsigned hb = hist[b];
        if (cum + hb >= Keff) break;
        cum += hb;
    }
    *above = cum;
    return (unsigned)b;
}

// ---- degree count + rank, against 2 XCD-partitioned replicas ----
// rep = XCC_ID & 1: blocks on XCDs {0,2,4,6} update replica 0, {1,3,5,7}
// replica 1 -> each replica's lines are touched by only 4 XCDs (halved
// cross-XCD sharing). rank packs rep in bit 31.
__global__ void count_kernel(const int* __restrict__ head,
                             unsigned* __restrict__ degiR, unsigned* __restrict__ rank) {
    int e = blockIdx.x * blockDim.x + threadIdx.x;
    if (e >= N_EDGES) return;
    unsigned rep = xcc_id() & 1u;
    unsigned old = atomicAdd(&degiR[rep * N_ENTITIES + head[e]], 1u);
    rank[e] = (rep << 31) | old;
}

// ---- proj = emb @ W_Q (clean streaming GEMM, no fused atomics) ----
__global__ __launch_bounds__(256) void proj_kernel(const float* __restrict__ emb,
                                                   const float* __restrict__ W,
                                                   float* __restrict__ proj) {
    __shared__ float part[4][16][64];
    const int t = threadIdx.x;
    const int c = t & 63;
    const int q = __builtin_amdgcn_readfirstlane(t >> 6);

    float Wreg[16];
#pragma unroll
    for (int j = 0; j < 16; ++j) Wreg[j] = W[(q * 16 + j) * 64 + c];

    const int base = blockIdx.x * 16;   // 200000 = 12500 * 16, exact
    const float* erow = emb + (size_t)base * 64 + q * 16;

    float acc[16];
#pragma unroll
    for (int r = 0; r < 16; ++r) acc[r] = 0.f;
#pragma unroll
    for (int r = 0; r < 16; ++r) {
#pragma unroll
        for (int j = 0; j < 16; ++j)
            acc[r] += erow[r * 64 + j] * Wreg[j];
    }
#pragma unroll
    for (int r = 0; r < 16; ++r) part[q][r][c] = acc[r];
    __syncthreads();
#pragma unroll
    for (int it = 0; it < 4; ++it) {
        int oi = t + it * 256;
        int r = oi >> 6, cc = oi & 63;
        float s = part[0][r][cc] + part[1][r][cc] + part[2][r][cc] + part[3][r][cc];
        proj[(size_t)(base + r) * 64 + cc] = s;
    }
}

// ---- scan step 1: block-local exclusive scan of (cnt0+cnt1) + block sums ----
__global__ void scan1_kernel(const unsigned* __restrict__ degiR, unsigned* __restrict__ start,
                             unsigned* __restrict__ bsum) {
    __shared__ unsigned s[256];
    int t = threadIdx.x, i = blockIdx.x * 256 + t;
    unsigned v = (i < N_ENTITIES) ? (degiR[i] + degiR[N_ENTITIES + i]) : 0u;
    s[t] = v;
    __syncthreads();
    for (int off = 1; off < 256; off <<= 1) {
        unsigned x = s[t];
        unsigned y = (t >= off) ? s[t - off] : 0u;
        __syncthreads();
        s[t] = x + y;
        __syncthreads();
    }
    if (i < N_ENTITIES) start[i] = s[t] - v;   // block-local exclusive
    if (t == 255) bsum[blockIdx.x] = s[t];
}

// ---- scan step 2+3 fused ----
__global__ __launch_bounds__(256) void scan23_kernel(const unsigned* __restrict__ bsum,
                                                     unsigned* __restrict__ start) {
    __shared__ unsigned part[4];
    const int b = blockIdx.x;
    const int t = threadIdx.x;
    unsigned s = 0;
    for (int j = t; j < b; j += 256) s += bsum[j];
#pragma unroll
    for (int off = 1; off < 64; off <<= 1) s += __shfl_xor(s, off, 64);
    if ((t & 63) == 0) part[t >> 6] = s;
    __syncthreads();
    unsigned prefix = part[0] + part[1] + part[2] + part[3];
    int i = b * 256 + t;
    if (i < N_ENTITIES) start[i] += prefix;
}

// ---- atomic-free scatter: slot = start[h] + (rep ? cnt0[h] : 0) + rankLocal ----
// rec = tail(18b)<<27 | rel(6b)<<21 | eid(21b)
__global__ void scatter_kernel(const int* __restrict__ head, const int* __restrict__ tail,
                               const int* __restrict__ etype,
                               const unsigned* __restrict__ rank,
                               const unsigned* __restrict__ start,
                               const unsigned* __restrict__ degiR,
                               u64* __restrict__ rec) {
    int i = blockIdx.x * blockDim.x + threadIdx.x;
    if (i >= N_EDGES) return;
    int h = head[i];
    unsigned rk = rank[i];
    unsigned slot = start[h] + ((rk >> 31) ? degiR[h] : 0u) + (rk & 0x7FFFFFFFu);
    u64 R = ((u64)(unsigned)tail[i] << 27) | ((u64)(unsigned)(etype[i] - 1) << 21) | (u64)(unsigned)i;
    rec[slot] = R;
}

// ---- CSR main pass, fully fused: logits + denom/deg/sumhead in-register,
// exp(lg) stashed in LDS, then second lane-per-edge loop emits scores +
// gumbel keys + edge stage-0 histogram. sumtail -> per-XCD replica. ----
__global__ __launch_bounds__(256) void node_pass(const float4* __restrict__ proj4,
                                                 const float4* __restrict__ rel4,
                                                 const u64* __restrict__ rec,
                                                 const unsigned* __restrict__ start,
                                                 const float* __restrict__ noise_u,
                                                 float* __restrict__ out_scores,
                                                 unsigned* __restrict__ keysE,
                                                 float* __restrict__ sumhead,
                                                 float* __restrict__ sumtailR,
                                                 unsigned* __restrict__ histE) {
    __shared__ float ex[4][CAP];
    __shared__ unsigned hE[256];
    hE[threadIdx.x] = 0;
    __syncthreads();

    float* strep = sumtailR + (size_t)(xcc_id() & 1u) * N_ITEMS;

    int node = (blockIdx.x * blockDim.x + threadIdx.x) >> 6;   // grid exact
    int w = threadIdx.x >> 6;
    int lane = threadIdx.x & 63;
    int slot = lane >> 4, sl = lane & 15;
    unsigned s = start[node];
    unsigned e1 = (node + 1 < N_ENTITIES) ? start[node + 1] : (unsigned)N_EDGES;
    unsigned len = e1 - s;
    float4 ph = proj4[(size_t)node * 16 + sl];
    float dsum = 0.f, lsum = 0.f;

    for (unsigned k0 = 0; k0 < len; k0 += 8) {
        unsigned ka = k0 + slot, kb = ka + 4;
        bool va = (ka < len), vb = (kb < len);
        u64 Ra = rec[s + (va ? ka : 0u)];
        u64 Rb = rec[s + (vb ? kb : 0u)];
        unsigned ta = (unsigned)(Ra >> 27), ra = ((unsigned)(Ra >> 21)) & 63u;
        unsigned tb = (unsigned)(Rb >> 27), rb = ((unsigned)(Rb >> 21)) & 63u;
        float4 pa = proj4[(size_t)ta * 16 + sl];
        float4 qa = rel4[(size_t)ra * 16 + sl];
        float4 pb = proj4[(size_t)tb * 16 + sl];
        float4 qb = rel4[(size_t)rb * 16 + sl];
        float xa = ph.x * pa.x * qa.x + ph.y * pa.y * qa.y + ph.z * pa.z * qa.z + ph.w * pa.w * qa.w;
        float xb = ph.x * pb.x * qb.x + ph.y * pb.y * qb.y + ph.z * pb.z * qb.z + ph.w * pb.w * qb.w;
        xa += __shfl_xor(xa, 1, 64);  xb += __shfl_xor(xb, 1, 64);
        xa += __shfl_xor(xa, 2, 64);  xb += __shfl_xor(xb, 2, 64);
        xa += __shfl_xor(xa, 4, 64);  xb += __shfl_xor(xb, 4, 64);
        xa += __shfl_xor(xa, 8, 64);  xb += __shfl_xor(xb, 8, 64);
        if (sl == 0) {
            if (va) {
                float lg = xa * SCALE;
                float E = __expf(lg);
                if (ka < CAP) ex[w][ka] = E;
                dsum += E;
                lsum += lg;
                if (ta < N_ITEMS) atomicAdd(&strep[ta], lg);
            }
            if (vb) {
                float lg = xb * SCALE;
                float E = __expf(lg);
                if (kb < CAP) ex[w][kb] = E;
                dsum += E;
                lsum += lg;
                if (tb < N_ITEMS) atomicAdd(&strep[tb], lg);
            }
        }
    }
    // fold the 4 slot-partials, broadcast dsum to all lanes
    dsum += __shfl_xor(dsum, 16, 64);
    dsum += __shfl_xor(dsum, 32, 64);
    lsum += __shfl_xor(lsum, 16, 64);
    lsum += __shfl_xor(lsum, 32, 64);
    dsum = __shfl(dsum, 0, 64);
    if (lane == 0) sumhead[node] = lsum;
    float flen = (float)len;
    __syncthreads();   // ex[] settled; also phase boundary for hE

    // loop 2: lane-per-edge epilogue
    for (unsigned k0 = 0; k0 < len; k0 += 64) {
        unsigned k = k0 + lane;
        bool valid = (k < len);
        unsigned bin = 0;
        if (valid) {
            u64 R = rec[s + k];
            unsigned eid = (unsigned)R & 0x1FFFFFu;
            float E = ex[w][k < CAP ? k : CAP - 1];
            float score = E / dsum * flen;
            float nu = noise_u[eid];
            unsigned kk = fkey(score - logf(-logf(nu)));
            out_scores[eid] = score;
            keysE[eid] = kk;
            bin = kk >> 24;
        }
        lds_hist_add(hE, bin, valid, lane);
    }
    __syncthreads();
    unsigned v = hE[threadIdx.x];
    if (v) atomicAdd(&histE[threadIdx.x], v);
}

// ---- item keys: fold sumhead + both sumtail replicas + item stage-0 hist ----
__global__ void item_kernel(const float* __restrict__ sumhead, const float* __restrict__ sumtailR,
                            unsigned* __restrict__ keysI, unsigned* __restrict__ histI) {
    __shared__ unsigned h[256];
    h[threadIdx.x] = 0;
    __syncthreads();
    int i = blockIdx.x * blockDim.x + threadIdx.x;
    int lane = threadIdx.x & 63;
    unsigned bin = 0;
    bool valid = (i < N_ITEMS);
    if (valid) {
        float s = sumhead[i] + sumtailR[i] + sumtailR[N_ITEMS + i];
        unsigned k = fkey(s);
        keysI[i] = k;
        bin = k >> 24;
    }
    lds_hist_add(h, bin, valid, lane);
    __syncthreads();
    unsigned v = h[threadIdx.x];
    if (v) atomicAdd(&histI[threadIdx.x], v);
}

// ---- radix stages 1,2 (grid.y: 0=edges, 1=items); hists [y][stage][256] ----
__global__ void hist_stage_kernel(const unsigned* __restrict__ keysE,
                                  const unsigned* __restrict__ keysI,
                                  unsigned* __restrict__ hists, int stage) {
    __shared__ unsigned h[256];
    for (int j = threadIdx.x; j < 256; j += blockDim.x) h[j] = 0;
    __syncthreads();
    const int y = blockIdx.y;
    const unsigned* keys = y ? keysI : keysE;
    const int n = y ? N_ITEMS : N_EDGES;
    const unsigned K = y ? K_ITEMS : K_EDGES;
    unsigned* H = hists + (size_t)y * 3 * 256;

    unsigned aboveA, prefix;
    unsigned binA = select_digit(H, K, &aboveA);
    if (stage == 1) {
        prefix = binA;
    } else {
        unsigned aboveB;
        unsigned binB = select_digit(H + 256, K - aboveA, &aboveB);
        prefix = (binA << 8) | binB;
    }
    const int shift = 24 - 8 * stage;
    unsigned* out = H + stage * 256;

    const int lane = threadIdx.x & 63;
    const int stride = gridDim.x * blockDim.x;
    for (int idx = blockIdx.x * blockDim.x + threadIdx.x; idx - lane < n; idx += stride) {
        bool valid = (idx < n);
        unsigned bin = 0;
        if (valid) {
            unsigned k = keys[idx];
            if ((k >> (shift + 8)) != prefix) valid = false;
            bin = (k >> shift) & 0xFFu;
        }
        lds_hist_add(h, bin, valid, lane);
    }
    __syncthreads();
    for (int j = threadIdx.x; j < 256; j += blockDim.x) {
        unsigned v = h[j];
        if (v) atomicAdd(&out[j], v);
    }
}

// ---- collect candidates >= 24-bit threshold ----
__global__ void collect_kernel(const unsigned* __restrict__ keysE,
                               const unsigned* __restrict__ keysI,
                               const unsigned* __restrict__ hists,
                               unsigned* __restrict__ counters, unsigned* __restrict__ cand) {
    const int y = blockIdx.y;
    const unsigned* keys = y ? keysI : keysE;
    const int n = y ? N_ITEMS : N_EDGES;
    const unsigned K = y ? K_ITEMS : K_EDGES;
    const unsigned* H = hists + (size_t)y * 3 * 256;
    unsigned aboveA, aboveB, aboveC;
    unsigned binA = select_digit(H, K, &aboveA);
    unsigned binB = select_digit(H + 256, K - aboveA, &aboveB);
    unsigned binC = select_digit(H + 512, K - aboveA - aboveB, &aboveC);
    const unsigned T = ((binA << 16) | (binB << 8) | binC) << 8;
    unsigned* cd = cand + (size_t)y * 2 * CAND_CAP;

    int i = blockIdx.x * blockDim.x + threadIdx.x;
    int stride = gridDim.x * blockDim.x;
    for (; i < n; i += stride) {
        unsigned k = keys[i];
        if (k >= T) {
            unsigned p = atomicAdd(&counters[y], 1u);
            if (p < (unsigned)CAND_CAP) { cd[2 * p] = k; cd[2 * p + 1] = (unsigned)i; }
        }
    }
}

// ---- exact rank among candidates (key desc, index asc); 2 blocks (y) ----
__global__ void final_topk_kernel(const unsigned* __restrict__ cand,
                                  const unsigned* __restrict__ counters,
                                  float* __restrict__ out_topkv, float* __restrict__ out_topki,
                                  float* __restrict__ out_itemv, float* __restrict__ out_itemi) {
    __shared__ unsigned sk[CAND_CAP];
    __shared__ unsigned si[CAND_CAP];
    const int y = blockIdx.x;
    const int K = y ? K_ITEMS : K_EDGES;
    float* outv = y ? out_itemv : out_topkv;
    float* outi = y ? out_itemi : out_topki;
    const unsigned* cd = cand + (size_t)y * 2 * CAND_CAP;
    unsigned m = counters[y];
    if (m > (unsigned)CAND_CAP) m = CAND_CAP;
    for (unsigned i = threadIdx.x; i < m; i += blockDim.x) {
        sk[i] = cd[2 * i];
        si[i] = cd[2 * i + 1];
    }
    __syncthreads();
    for (unsigned i = threadIdx.x; i < m; i += blockDim.x) {
        unsigned ki = sk[i], xi = si[i];
        int r = 0;
        for (unsigned j = 0; j < m; ++j) {
            unsigned kj = sk[j];
            if (kj > ki || (kj == ki && si[j] < xi)) r++;
        }
        if (r < K) {
            outv[r] = funkey(ki);
            outi[r] = (float)xi;
        }
    }
}

extern "C" void kernel_launch(void* const* d_in, const int* in_sizes, int n_in,
                              void* d_out, int out_size, void* d_ws, size_t ws_size,
                              hipStream_t stream) {
    (void)in_sizes; (void)n_in; (void)out_size; (void)ws_size;
    const float* emb    = (const float*)d_in[0];
    const float* W      = (const float*)d_in[1];
    const float* rel    = (const float*)d_in[2];
    const float* noise  = (const float*)d_in[3];
    const int*   eidx   = (const int*)d_in[4];
    const int*   etype  = (const int*)d_in[5];
    const int* head = eidx;
    const int* tail = eidx + N_EDGES;

    float* out        = (float*)d_out;
    float* out_scores = out;
    float* out_topkv  = out + N_EDGES;
    float* out_topki  = out + N_EDGES + K_EDGES;
    float* out_itemv  = out + N_EDGES + 2 * K_EDGES;
    float* out_itemi  = out + N_EDGES + 2 * K_EDGES + K_ITEMS;

    float* ws = (float*)d_ws;
    size_t o = 0;
    float*    proj    = ws + o;               o += (size_t)N_ENTITIES * DIM;      // 12.8M
    // rank (count->scatter) then keysE (node_pass->collect): disjoint lifetimes
    unsigned* rank    = (unsigned*)(ws + o);
    unsigned* keysE   = (unsigned*)(ws + o);  o += N_EDGES;                        // 1.5M
    u64*      rec     = (u64*)(ws + o);
    unsigned* keysI   = (unsigned*)rec;       o += 2 * (size_t)N_EDGES;            // 3.0M (keysI after node_pass)
    unsigned* start   = (unsigned*)(ws + o);  o += N_ENTITIES;                     // 0.2M
    unsigned* degiR   = (unsigned*)(ws + o);  o += 2 * (size_t)N_ENTITIES;         // 0.4M (memset1 begins)
    float*    sumtailR= (float*)degiR;        // 2*N_ITEMS floats, re-zeroed after scatter
    unsigned* hists   = (unsigned*)(ws + o);  o += 2 * 3 * 256;
    unsigned* counters= (unsigned*)(ws + o);  o += 2;                              // memset1 ends
    float*    sumhead = ws + o;               o += N_ENTITIES;                     // 0.2M
    unsigned* bsum    = (unsigned*)(ws + o);  o += 1024;
    unsigned* cand    = (unsigned*)(ws + o);  o += 2 * 2 * CAND_CAP;
    // total ~18.12M floats = 72.5 MB (< 73.8 MB proven-safe)

    // zero: degiR + hists + counters (contiguous)
    hipMemsetAsync(degiR, 0, (2 * (size_t)N_ENTITIES + 2 * 3 * 256 + 2) * 4, stream);
    // degree count + rank vs 2 XCD-partitioned replicas
    hipLaunchKernelGGL(count_kernel, dim3((N_EDGES + 255) / 256), dim3(256), 0, stream,
                       head, degiR, rank);
    // clean projection GEMM
    hipLaunchKernelGGL(proj_kernel, dim3(12500), dim3(256), 0, stream, emb, W, proj);
    // exclusive scan of (cnt0+cnt1) -> start
    hipLaunchKernelGGL(scan1_kernel, dim3(NSCANB), dim3(256), 0, stream, degiR, start, bsum);
    hipLaunchKernelGGL(scan23_kernel, dim3(NSCANB), dim3(256), 0, stream, bsum, start);
    // atomic-free scatter into CSR
    hipLaunchKernelGGL(scatter_kernel, dim3((N_EDGES + 255) / 256), dim3(256), 0, stream,
                       head, tail, etype, rank, start, degiR, rec);
    // re-zero the sumtail replicas (alias degiR, which scatter just finished reading)
    hipMemsetAsync(sumtailR, 0, 2 * (size_t)N_ITEMS * 4, stream);
    // fused CSR main pass: logits+denom+sumhead+scores+keys+edge hist
    hipLaunchKernelGGL(node_pass, dim3(N_ENTITIES / 4), dim3(256), 0, stream,
                       (const float4*)proj, (const float4*)rel, rec, start, noise,
                       out_scores, keysE, sumhead, sumtailR, hists);
    // item keys + item stage-0 hist
    hipLaunchKernelGGL(item_kernel, dim3((N_ITEMS + 255) / 256), dim3(256), 0, stream,
                       sumhead, sumtailR, keysI, hists + 3 * 256);
    // shared top-k pipeline
    hipLaunchKernelGGL(hist_stage_kernel, dim3(512, 2), dim3(256), 0, stream,
                       keysE, keysI, hists, 1);
    hipLaunchKernelGGL(hist_stage_kernel, dim3(512, 2), dim3(256), 0, stream,
                       keysE, keysI, hists, 2);
    hipLaunchKernelGGL(collect_kernel, dim3(512, 2), dim3(256), 0, stream,
                       keysE, keysI, hists, counters, cand);
    hipLaunchKernelGGL(final_topk_kernel, dim3(2), dim3(1024), 0, stream,
                       cand, counters, out_topkv, out_topki, out_itemv, out_itemi);
}